// Round 11
// baseline (1101.016 us; speedup 1.0000x reference)
//
#include <hip/hip_runtime.h>
#include <stdint.h>

#define DX 1024
#define NB 64
#define DY 10
#define NJK 100

typedef unsigned short ushort_t;
typedef __attribute__((ext_vector_type(8))) short short8;
typedef __attribute__((ext_vector_type(4))) float f32x4;
typedef __attribute__((ext_vector_type(16))) float f32x16;

#define VMCNT6 asm volatile("s_waitcnt vmcnt(6)" ::: "memory")
#define VMCNT5 asm volatile("s_waitcnt vmcnt(5)" ::: "memory")
#define VMCNT4 asm volatile("s_waitcnt vmcnt(4)" ::: "memory")
#define VMCNT0 asm volatile("s_waitcnt vmcnt(0)" ::: "memory")
#define LGKM0 asm volatile("s_waitcnt lgkmcnt(0)" ::: "memory")
#define CFENCE asm volatile("" ::: "memory")

__device__ __forceinline__ unsigned short f2bf(float f) {
  unsigned int u = __builtin_bit_cast(unsigned int, f);
  u += 0x7fffu + ((u >> 16) & 1u);
  return (unsigned short)(u >> 16);
}
__device__ __forceinline__ float bf2f(unsigned short h) {
  unsigned int u = ((unsigned int)h) << 16;
  return __builtin_bit_cast(float, u);
}
__device__ __forceinline__ void gload16(const void* g, void* l) {
  __builtin_amdgcn_global_load_lds((const __attribute__((address_space(1))) unsigned int*)g,
                                   (__attribute__((address_space(3))) unsigned int*)l, 16, 0, 0);
}

// ---------------------------------------------------------------------------
// rho_work: one pass over rho for one p (callable from standalone or mega):
//   R2[p][jk(112 pad)][m(1024)] bf16 ; S[p][m] = sum_j rho[p][j][m][j] (f32)
// Threads >=256 idle (barrier-participating only).
// ---------------------------------------------------------------------------
__device__ __forceinline__ void rho_work(int p, int t, const float* __restrict__ rho,
                                         ushort_t* __restrict__ R2, float* __restrict__ S,
                                         ushort_t* R_s) {
  const float* rp = rho + (size_t)p * (DY * DX * DY);
  ushort_t* R2p = R2 + (size_t)p * (112 * 1024);
  int m = (t & 255) >> 1, h = t & 1;
  bool act = t < 256;

  for (int mc = 0; mc < 8; ++mc) {
    __syncthreads();
    if (act) {
      float ssum = 0.f;
#pragma unroll
      for (int j = 0; j < DY; ++j) {
        const float* bj = rp + (size_t)j * (DX * DY) + (size_t)(mc * 128 + m) * DY;
        const float4 q = *(const float4*)(bj + h * 4);
        const float e = bj[8 + h];
        int rb = j * DY + h * 4;
        R_s[((rb + 0) * 128 + m) ^ (((rb + 0) & 15) << 3)] = f2bf(q.x);
        R_s[((rb + 1) * 128 + m) ^ (((rb + 1) & 15) << 3)] = f2bf(q.y);
        R_s[((rb + 2) * 128 + m) ^ (((rb + 2) & 15) << 3)] = f2bf(q.z);
        R_s[((rb + 3) * 128 + m) ^ (((rb + 3) & 15) << 3)] = f2bf(q.w);
        int r8 = j * DY + 8 + h;
        R_s[(r8 * 128 + m) ^ ((r8 & 15) << 3)] = f2bf(e);
        if (h == 0) {
          if (j == 0) ssum += q.x;
          if (j == 1) ssum += q.y;
          if (j == 2) ssum += q.z;
          if (j == 3) ssum += q.w;
          if (j == 8) ssum += e;
        } else {
          if (j == 4) ssum += q.x;
          if (j == 5) ssum += q.y;
          if (j == 6) ssum += q.z;
          if (j == 7) ssum += q.w;
          if (j == 9) ssum += e;
        }
      }
      ssum += __shfl_xor(ssum, 1, 64);
      if (h == 0) S[(size_t)p * DX + mc * 128 + m] = ssum;
    }
    __syncthreads();
    if (act) {
#pragma unroll
      for (int i = 0; i < 7; ++i) {
        int c = i * 256 + (t & 255);
        int row = c >> 4, sl = c & 15;
        uint4 v = make_uint4(0u, 0u, 0u, 0u);
        if (row < NJK) v = *(const uint4*)&R_s[(row * 128 + sl * 8) ^ ((row & 15) << 3)];
        *(uint4*)(R2p + (size_t)row * 1024 + mc * 128 + sl * 8) = v;
      }
    }
  }
}

__launch_bounds__(256)
__global__ void p0_rho_k(const float* __restrict__ rho, ushort_t* __restrict__ R2,
                         float* __restrict__ S) {
  __shared__ ushort_t R_s[112 * 128];
  rho_work(blockIdx.x, threadIdx.x, rho, R2, S, R_s);
}

// ---------------------------------------------------------------------------
// P0a: emit BOTH operands of K1 pre-split (unchanged from R10):
//  XHL [b][kt(32)][m(1024)][8 slots x 16B] : record = [Ah k0..31 | Al k0..31]
//  XtHL[b][kt(32)][p(1024)][8 slots x 16B] : same for X^T rows.
// ---------------------------------------------------------------------------
__launch_bounds__(256)
__global__ void p0_split(const float* __restrict__ X,
                         ushort_t* __restrict__ XHL, ushort_t* __restrict__ XtHL) {
  __shared__ float T[64][65];
  int blk = blockIdx.x;
  int bl = blk >> 8;
  int tt = blk & 255;
  int r0 = (tt >> 4) << 6;
  int c0 = (tt & 15) << 6;
  const float* Xb = X + (size_t)bl * DX * DX;
  int t = threadIdx.x;
  int r = t >> 4, c = t & 15;
#pragma unroll
  for (int s = 0; s < 4; ++s) {
    const float4 v = *(const float4*)(Xb + (size_t)(r0 + r + 16 * s) * DX + c0 + c * 4);
    T[r + 16 * s][c * 4 + 0] = v.x;
    T[r + 16 * s][c * 4 + 1] = v.y;
    T[r + 16 * s][c * 4 + 2] = v.z;
    T[r + 16 * s][c * 4 + 3] = v.w;
  }
  __syncthreads();
  int s8 = t & 7;
  int rw = t >> 3;
  int isLo = s8 >> 2, q = s8 & 3;
#pragma unroll
  for (int ktl = 0; ktl < 2; ++ktl) {
#pragma unroll
    for (int sp = 0; sp < 2; ++sp) {
      int loc = rw + sp * 32;
      {
        unsigned short hh8[8];
#pragma unroll
        for (int e = 0; e < 8; ++e) {
          float x = T[loc][ktl * 32 + q * 8 + e];
          unsigned short hh = f2bf(x);
          hh8[e] = isLo ? f2bf(x - bf2f(hh)) : hh;
        }
        int kt = (c0 >> 5) + ktl;
        size_t off = (((size_t)bl * 32 + kt) * 1024 + (r0 + loc)) * 64 + s8 * 8;
        uint4 v;
        v.x = (unsigned)hh8[0] | ((unsigned)hh8[1] << 16);
        v.y = (unsigned)hh8[2] | ((unsigned)hh8[3] << 16);
        v.z = (unsigned)hh8[4] | ((unsigned)hh8[5] << 16);
        v.w = (unsigned)hh8[6] | ((unsigned)hh8[7] << 16);
        *(uint4*)(XHL + off) = v;
      }
      {
        unsigned short hh8[8];
#pragma unroll
        for (int e = 0; e < 8; ++e) {
          float x = T[ktl * 32 + q * 8 + e][loc];
          unsigned short hh = f2bf(x);
          hh8[e] = isLo ? f2bf(x - bf2f(hh)) : hh;
        }
        int kt = (r0 >> 5) + ktl;
        size_t off = (((size_t)bl * 32 + kt) * 1024 + (c0 + loc)) * 64 + s8 * 8;
        uint4 v;
        v.x = (unsigned)hh8[0] | ((unsigned)hh8[1] << 16);
        v.y = (unsigned)hh8[2] | ((unsigned)hh8[3] << 16);
        v.z = (unsigned)hh8[4] | ((unsigned)hh8[5] << 16);
        v.w = (unsigned)hh8[6] | ((unsigned)hh8[7] << 16);
        *(uint4*)(XtHL + off) = v;
      }
    }
  }
}

// ---------------------------------------------------------------------------
// k1_body: A[b]=X[b]@X[b], 3-pass split-bf16, 256x256 tile, BK=32, 8 waves.
// R10's 8-phase K-step UNCHANGED.  Epilogue: Ah AND Al -> [p][b][m] via
// two LDS-transpose passes (trace moved to k2t; no S dependency).
// ---------------------------------------------------------------------------
__device__ __forceinline__ void k1_body(ushort_t* lds, int wg, int cpx, int bg,
                                        const ushort_t* __restrict__ XHL,
                                        const ushort_t* __restrict__ XtHL,
                                        ushort_t* __restrict__ Ahg,
                                        ushort_t* __restrict__ Alg) {
  int gt = (wg & 7) * cpx + (wg >> 3);  // XCD-chunked
  int bl = gt >> 4, tile = gt & 15;
  int b = bg + bl;
  int m0 = (tile >> 2) << 8, p0 = (tile & 3) << 8;
  int t = threadIdx.x;
  int wv = t >> 6, lane = t & 63, l31 = lane & 31, hi8 = lane >> 5;
  int wm = (wv >> 2) << 7, wp = (wv & 3) << 6;

  f32x16 acc[4][2];
#pragma unroll
  for (int mi = 0; mi < 4; ++mi)
#pragma unroll
    for (int ni = 0; ni < 2; ++ni)
#pragma unroll
      for (int e = 0; e < 16; ++e) acc[mi][ni][e] = 0.f;

  int lam = lane >> 3;
  int lsl = (lane & 7) ^ lam;
  const ushort_t* Asrc = XHL + ((size_t)bl * 32 * 1024 + m0) * 64 + (size_t)lsl * 8;
  const ushort_t* Bsrc = XtHL + ((size_t)bl * 32 * 1024 + p0) * 64 + (size_t)lsl * 8;
  int ldsw = (t & ~63) * 8;

  auto stageA2 = [&](int kt, int half) {
    int buf = (kt & 1) << 15;
    size_t ko = (size_t)kt * 65536;
#pragma unroll
    for (int i = half * 2; i < half * 2 + 2; ++i) {
      int rr = (i << 6) + (wv << 3) + lam;
      gload16(Asrc + ko + (size_t)rr * 64, &lds[buf + (i << 12) + ldsw]);
    }
  };
  auto stageB2 = [&](int kt, int half) {
    int buf = (kt & 1) << 15;
    size_t ko = (size_t)kt * 65536;
#pragma unroll
    for (int i = half * 2; i < half * 2 + 2; ++i) {
      int rr = (i << 6) + (wv << 3) + lam;
      gload16(Bsrc + ko + (size_t)rr * 64, &lds[buf + 16384 + (i << 12) + ldsw]);
    }
  };
  auto readB = [&](int buf, int kc, short8* bh, short8* blo) {
#pragma unroll
    for (int ni = 0; ni < 2; ++ni) {
      int p = wp + (ni << 5) + l31;
      int rowb = buf + 16384 + p * 64;
      bh[ni] = *(const short8*)&lds[rowb + (((kc * 2 + hi8) ^ (p & 7)) << 3)];
      blo[ni] = *(const short8*)&lds[rowb + (((4 + kc * 2 + hi8) ^ (p & 7)) << 3)];
    }
  };
  auto readA2 = [&](int buf, int kc, int mi, short8& a, short8& l) {
    int m = wm + (mi << 5) + l31;
    int rowa = buf + m * 64;
    a = *(const short8*)&lds[rowa + (((kc * 2 + hi8) ^ (m & 7)) << 3)];
    l = *(const short8*)&lds[rowa + (((4 + kc * 2 + hi8) ^ (m & 7)) << 3)];
  };
  auto mfma6 = [&](int mi, const short8& a, const short8& l,
                   const short8* bh, const short8* blo) {
    __builtin_amdgcn_s_setprio(1);
#pragma unroll
    for (int ni = 0; ni < 2; ++ni) {
      acc[mi][ni] = __builtin_amdgcn_mfma_f32_32x32x16_bf16(a, bh[ni], acc[mi][ni], 0, 0, 0);
      acc[mi][ni] = __builtin_amdgcn_mfma_f32_32x32x16_bf16(a, blo[ni], acc[mi][ni], 0, 0, 0);
      acc[mi][ni] = __builtin_amdgcn_mfma_f32_32x32x16_bf16(l, bh[ni], acc[mi][ni], 0, 0, 0);
    }
    __builtin_amdgcn_s_setprio(0);
  };

  stageA2(0, 0);
  stageA2(0, 1);
  stageB2(0, 0);
  stageB2(0, 1);
  VMCNT0;
  __builtin_amdgcn_s_barrier();

#pragma unroll 1
  for (int kt = 0; kt < 32; ++kt) {
    int buf = (kt & 1) << 15;
    short8 bh[2], blo[2], a, l;
    readB(buf, 0, bh, blo);
    readA2(buf, 0, 0, a, l);
    if (kt < 31) stageA2(kt + 1, 0);
    CFENCE; __builtin_amdgcn_s_barrier(); LGKM0; __builtin_amdgcn_sched_barrier(0);
    mfma6(0, a, l, bh, blo);
    readA2(buf, 0, 1, a, l);
    if (kt < 31) stageA2(kt + 1, 1);
    CFENCE; __builtin_amdgcn_s_barrier(); LGKM0; __builtin_amdgcn_sched_barrier(0);
    mfma6(1, a, l, bh, blo);
    readA2(buf, 0, 2, a, l);
    if (kt < 31) stageB2(kt + 1, 0);
    CFENCE; __builtin_amdgcn_s_barrier(); LGKM0; __builtin_amdgcn_sched_barrier(0);
    mfma6(2, a, l, bh, blo);
    readA2(buf, 0, 3, a, l);
    if (kt < 31) stageB2(kt + 1, 1);
    CFENCE; __builtin_amdgcn_s_barrier(); LGKM0; __builtin_amdgcn_sched_barrier(0);
    mfma6(3, a, l, bh, blo);
    readB(buf, 1, bh, blo);
    readA2(buf, 1, 0, a, l);
    CFENCE; __builtin_amdgcn_s_barrier(); LGKM0; __builtin_amdgcn_sched_barrier(0);
    mfma6(0, a, l, bh, blo);
    readA2(buf, 1, 1, a, l);
    if (kt < 31) { VMCNT4; }
    CFENCE; __builtin_amdgcn_s_barrier(); LGKM0; __builtin_amdgcn_sched_barrier(0);
    mfma6(1, a, l, bh, blo);
    readA2(buf, 1, 2, a, l);
    CFENCE; __builtin_amdgcn_s_barrier(); LGKM0; __builtin_amdgcn_sched_barrier(0);
    mfma6(2, a, l, bh, blo);
    readA2(buf, 1, 3, a, l);
    VMCNT0;
    CFENCE; __builtin_amdgcn_s_barrier(); LGKM0; __builtin_amdgcn_sched_barrier(0);
    mfma6(3, a, l, bh, blo);
  }

  // ---- epilogue pass 1: Ah -> LDS [p][m] swizzled -> coalesced stores ----
  __syncthreads();
#pragma unroll
  for (int mi = 0; mi < 4; ++mi)
#pragma unroll
    for (int ni = 0; ni < 2; ++ni) {
      int p = wp + (ni << 5) + l31;
#pragma unroll
      for (int rg = 0; rg < 4; ++rg) {
        int m = wm + (mi << 5) + 8 * rg + 4 * hi8;
        unsigned int h0 = f2bf(acc[mi][ni][rg * 4 + 0]);
        unsigned int h1 = f2bf(acc[mi][ni][rg * 4 + 1]);
        unsigned int h2 = f2bf(acc[mi][ni][rg * 4 + 2]);
        unsigned int h3 = f2bf(acc[mi][ni][rg * 4 + 3]);
        int idx = p * 256 + (((m >> 3) ^ (p & 7)) << 3) + (m & 7);
        *(uint2*)&lds[idx] = make_uint2(h0 | (h1 << 16), h2 | (h3 << 16));
      }
    }
  __syncthreads();
#pragma unroll
  for (int i = 0; i < 16; ++i) {
    int cc = i * 512 + t;
    int row = cc >> 5, sl = cc & 31;
    int idx = row * 256 + ((sl ^ (row & 7)) << 3);
    uint4 v = *(const uint4*)&lds[idx];
    *(uint4*)(Ahg + ((size_t)(p0 + row) * NB + b) * DX + m0 + sl * 8) = v;
  }
  __syncthreads();
  // ---- epilogue pass 2: Al (residual) -> same transpose -> Alg ----
#pragma unroll
  for (int mi = 0; mi < 4; ++mi)
#pragma unroll
    for (int ni = 0; ni < 2; ++ni) {
      int p = wp + (ni << 5) + l31;
#pragma unroll
      for (int rg = 0; rg < 4; ++rg) {
        int m = wm + (mi << 5) + 8 * rg + 4 * hi8;
        unsigned int l0, l1, l2, l3;
        {
          float a0 = acc[mi][ni][rg * 4 + 0], a1 = acc[mi][ni][rg * 4 + 1];
          float a2 = acc[mi][ni][rg * 4 + 2], a3 = acc[mi][ni][rg * 4 + 3];
          l0 = f2bf(a0 - bf2f(f2bf(a0)));
          l1 = f2bf(a1 - bf2f(f2bf(a1)));
          l2 = f2bf(a2 - bf2f(f2bf(a2)));
          l3 = f2bf(a3 - bf2f(f2bf(a3)));
        }
        int idx = p * 256 + (((m >> 3) ^ (p & 7)) << 3) + (m & 7);
        *(uint2*)&lds[idx] = make_uint2(l0 | (l1 << 16), l2 | (l3 << 16));
      }
    }
  __syncthreads();
#pragma unroll
  for (int i = 0; i < 16; ++i) {
    int cc = i * 512 + t;
    int row = cc >> 5, sl = cc & 31;
    int idx = row * 256 + ((sl ^ (row & 7)) << 3);
    uint4 v = *(const uint4*)&lds[idx];
    *(uint4*)(Alg + ((size_t)(p0 + row) * NB + b) * DX + m0 + sl * 8) = v;
  }
}

// Mega launch: 16-bid groups: bids g*16+0..7 -> k1 (wg=g*8+r, preserves
// wg%8 == bid%8 for XCD swizzle); bids g*16+8..15 -> rho (p=g*8+r-8).
__launch_bounds__(512, 2)
__global__ void mega_k1_rho(const float* __restrict__ rho, ushort_t* __restrict__ R2,
                            float* __restrict__ S,
                            const ushort_t* __restrict__ XHL,
                            const ushort_t* __restrict__ XtHL,
                            ushort_t* __restrict__ Ahg, ushort_t* __restrict__ Alg) {
  __shared__ ushort_t lds[65536];
  int bid = blockIdx.x;
  int g = bid >> 4, r = bid & 15;
  if (r < 8) {
    k1_body(lds, g * 8 + r, 128, 0, XHL, XtHL, Ahg, Alg);
  } else {
    rho_work(g * 8 + (r - 8), threadIdx.x, rho, R2, S, lds);
  }
}

__launch_bounds__(512, 2)
__global__ void k1_kernel(const ushort_t* __restrict__ XHL,
                          const ushort_t* __restrict__ XtHL,
                          ushort_t* __restrict__ Ahg, ushort_t* __restrict__ Alg, int bg) {
  __shared__ ushort_t lds[65536];
  k1_body(lds, blockIdx.x, gridDim.x >> 3, bg, XHL, XtHL, Ahg, Alg);
}

// ---------------------------------------------------------------------------
// k2_mega: even bids -> numerator (R10 k2 verbatim); odd bids -> k2t trace:
//   part_tr[p][b] = sum_m (Ah+Al)[p,b,m] * S[p,m]   (f32, R2-proven numerics)
// ---------------------------------------------------------------------------
__launch_bounds__(256)
__global__ void k2_mega(const ushort_t* __restrict__ R2,
                        const ushort_t* __restrict__ Ahg,
                        const ushort_t* __restrict__ Alg,
                        const float* __restrict__ S,
                        float* __restrict__ part_rho, float* __restrict__ part_tr) {
  __shared__ ushort_t lds[22528];
  __shared__ float red[256];
  int bid = blockIdx.x;
  int t = threadIdx.x;

  if (bid & 1) {
    // ---- k2t: trace partial for p ----
    int p = bid >> 1;
    int b = t >> 2, q = t & 3;
    const ushort_t* ah = Ahg + ((size_t)p * NB + b) * DX + q * 256;
    const ushort_t* al = Alg + ((size_t)p * NB + b) * DX + q * 256;
    const float* sv = S + (size_t)p * DX + q * 256;
    float ts = 0.f;
#pragma unroll 4
    for (int i = 0; i < 32; ++i) {
      uint4 hv = *(const uint4*)(ah + i * 8);
      uint4 lv = *(const uint4*)(al + i * 8);
      float4 s0 = *(const float4*)(sv + i * 8);
      float4 s1 = *(const float4*)(sv + i * 8 + 4);
      unsigned hw[4] = {hv.x, hv.y, hv.z, hv.w};
      unsigned lw[4] = {lv.x, lv.y, lv.z, lv.w};
      float ss[8] = {s0.x, s0.y, s0.z, s0.w, s1.x, s1.y, s1.z, s1.w};
#pragma unroll
      for (int e = 0; e < 4; ++e) {
        float a0 = bf2f((unsigned short)(hw[e] & 0xffff)) + bf2f((unsigned short)(lw[e] & 0xffff));
        float a1 = bf2f((unsigned short)(hw[e] >> 16)) + bf2f((unsigned short)(lw[e] >> 16));
        ts += a0 * ss[2 * e] + a1 * ss[2 * e + 1];
      }
    }
    red[t] = ts;
    __syncthreads();
    if (t < 64)
      part_tr[(size_t)p * NB + t] = red[4 * t] + red[4 * t + 1] + red[4 * t + 2] + red[4 * t + 3];
    return;
  }

  // ---- k2 numerator (R10 verbatim) ----
  int p = bid >> 1;
  int wv = t >> 6, lane = t & 63, lr = lane & 15, lg = lane >> 4;
  const ushort_t* R2p = R2 + (size_t)p * (112 * 1024);
  const ushort_t* Ahp = Ahg + (size_t)p * (NB * DX);

  f32x4 acc[7];
#pragma unroll
  for (int n = 0; n < 7; ++n)
#pragma unroll
    for (int i = 0; i < 4; ++i) acc[n][i] = 0.f;

  auto stage = [&](int mc) {
    int buf = (mc & 1) * 11264;
#pragma unroll
    for (int i = 0; i < 2; ++i) {
      int c = i * 256 + t;
      int br = c >> 3, sl = c & 7;
      int lsl = sl ^ (br & 7);
      gload16(Ahp + (size_t)br * DX + mc * 64 + lsl * 8,
              &lds[buf + (i * 256 + (t & ~63)) * 8]);
    }
#pragma unroll
    for (int i = 0; i < 4; ++i) {
      int c = i * 256 + t;
      if (c < 896) {
        int row = c >> 3, sl = c & 7;
        int lsl = sl ^ (row & 7);
        gload16(R2p + (size_t)row * 1024 + mc * 64 + lsl * 8,
                &lds[buf + 4096 + (i * 256 + (t & ~63)) * 8]);
      }
    }
  };

  stage(0);
#pragma unroll 1
  for (int mc = 0; mc < 16; ++mc) {
    int buf = (mc & 1) * 11264;
    if (mc < 15) {
      stage(mc + 1);
      if (wv < 2) { VMCNT6; } else { VMCNT5; }
    } else {
      VMCNT0;
    }
    __builtin_amdgcn_s_barrier();
    CFENCE;
#pragma unroll
    for (int s = 0; s < 2; ++s) {
      int slot = s * 4 + lg;
      int ra = 16 * wv + lr;
      short8 af = *(const short8*)&lds[buf + ra * 64 + ((slot ^ (ra & 7)) << 3)];
      __builtin_amdgcn_s_setprio(1);
#pragma unroll
      for (int n = 0; n < 7; ++n) {
        int rb = 16 * n + lr;
        short8 bf = *(const short8*)&lds[buf + 4096 + rb * 64 + ((slot ^ (rb & 7)) << 3)];
        acc[n] = __builtin_amdgcn_mfma_f32_16x16x32_bf16(af, bf, acc[n], 0, 0, 0);
      }
      __builtin_amdgcn_s_setprio(0);
    }
    CFENCE;
    __builtin_amdgcn_s_barrier();
  }
#pragma unroll
  for (int n = 0; n < 7; ++n) {
    int col = 16 * n + lr;
    if (col < NJK) {
#pragma unroll
      for (int i = 0; i < 4; ++i) {
        int b_ = 16 * wv + lg * 4 + i;
        part_rho[((size_t)p * NB + b_) * NJK + col] = acc[n][i];
      }
    }
  }
}

// ---------------------------------------------------------------------------
// K3a: partial p-reduction; K3b: finish + divide by exact trace (1024 parts).
// ---------------------------------------------------------------------------
__launch_bounds__(128)
__global__ void k3a(const float* __restrict__ part_rho, float* __restrict__ ws2) {
  int blk = blockIdx.x;
  int b = blk >> 1, h = blk & 1;
  int t = threadIdx.x;
  if (t >= NJK) return;
  float s = 0.f;
  for (int pp = 0; pp < 512; ++pp)
    s += part_rho[((size_t)(h * 512 + pp) * NB + b) * NJK + t];
  ws2[(size_t)(h * NB + b) * 128 + t] = s;
}

__launch_bounds__(128)
__global__ void k3b(const float* __restrict__ ws2, const float* __restrict__ part_tr,
                    float* __restrict__ out) {
  __shared__ float red[128];
  int b = blockIdx.x;
  int t = threadIdx.x;
  float tr = 0.f;
  for (int pp = t; pp < 1024; pp += 128) tr += part_tr[(size_t)pp * NB + b];
  red[t] = tr;
  __syncthreads();
  for (int off = 64; off > 0; off >>= 1) {
    if (t < off) red[t] += red[t + off];
    __syncthreads();
  }
  if (t < NJK) {
    float v = ws2[(size_t)b * 128 + t] + ws2[(size_t)(NB + b) * 128 + t];
    out[b * NJK + t] = v / red[0];
  }
}

extern "C" void kernel_launch(void* const* d_in, const int* in_sizes, int n_in,
                              void* d_out, int out_size, void* d_ws, size_t ws_size,
                              hipStream_t stream) {
  const float* X = (const float*)d_in[0];
  const float* rho = (const float*)d_in[1];
  float* out = (float*)d_out;
  char* ws = (char*)d_ws;

  const size_t MB = 1048576ull;
  const size_t need_big = 997 * MB;
  const size_t need_small = 613 * MB;

  if (ws_size >= need_big) {
    ushort_t* XHL = (ushort_t*)(ws);              // 256 MiB
    ushort_t* XtHL = (ushort_t*)(ws + 256 * MB);  // 256 MiB
    ushort_t* Ahg = (ushort_t*)(ws + 512 * MB);   // 128 MiB
    ushort_t* Alg = (ushort_t*)(ws + 640 * MB);   // 128 MiB
    ushort_t* R2 = (ushort_t*)(ws + 768 * MB);    // 224 MiB
    float* S = (float*)(ws + 992 * MB);           // 4 MiB
    float* part_tr = (float*)(ws + 996 * MB);     // 256 KiB
    float* part_rho = (float*)(ws);               // overlays XHL (dead after mega)
    float* ws2 = (float*)(ws + 32 * MB);

    hipLaunchKernelGGL(p0_split, dim3(16384), dim3(256), 0, stream, X, XHL, XtHL);
    hipLaunchKernelGGL(mega_k1_rho, dim3(2048), dim3(512), 0, stream,
                       rho, R2, S, XHL, XtHL, Ahg, Alg);
    hipLaunchKernelGGL(k2_mega, dim3(2048), dim3(256), 0, stream,
                       R2, Ahg, Alg, S, part_rho, part_tr);
    hipLaunchKernelGGL(k3a, dim3(128), dim3(128), 0, stream, part_rho, ws2);
    hipLaunchKernelGGL(k3b, dim3(64), dim3(128), 0, stream, ws2, part_tr, out);
  } else {
    ushort_t* XHL = (ushort_t*)(ws);              // 64 MiB (per 16-batch group)
    ushort_t* XtHL = (ushort_t*)(ws + 64 * MB);   // 64 MiB
    ushort_t* Ahg = (ushort_t*)(ws + 128 * MB);   // 128 MiB
    ushort_t* Alg = (ushort_t*)(ws + 256 * MB);   // 128 MiB
    ushort_t* R2 = (ushort_t*)(ws + 384 * MB);    // 224 MiB
    float* S = (float*)(ws + 608 * MB);           // 4 MiB
    float* part_tr = (float*)(ws + 612 * MB);     // 256 KiB
    float* part_rho = (float*)(ws);               // overlays XHL
    float* ws2 = (float*)(ws + 32 * MB);
    if (ws_size < need_small) return;

    hipLaunchKernelGGL(p0_rho_k, dim3(1024), dim3(256), 0, stream, rho, R2, S);
    for (int g = 0; g < 4; ++g) {
      hipLaunchKernelGGL(p0_split, dim3(4096), dim3(256), 0, stream,
                         X + (size_t)g * 16 * DX * DX, XHL, XtHL);
      hipLaunchKernelGGL(k1_kernel, dim3(256), dim3(512), 0, stream,
                         XHL, XtHL, Ahg, Alg, g * 16);
    }
    hipLaunchKernelGGL(k2_mega, dim3(2048), dim3(256), 0, stream,
                       R2, Ahg, Alg, S, part_rho, part_tr);
    hipLaunchKernelGGL(k3a, dim3(128), dim3(128), 0, stream, part_rho, ws2);
    hipLaunchKernelGGL(k3b, dim3(64), dim3(128), 0, stream, ws2, part_tr, out);
  }
}

// Round 12
// 734.506 us; speedup vs baseline: 1.4990x; 1.4990x over previous
//
#include <hip/hip_runtime.h>
#include <stdint.h>

#define DX 1024
#define NB 64
#define DY 10
#define NJK 100

typedef unsigned short ushort_t;
typedef __attribute__((ext_vector_type(8))) short short8;
typedef __attribute__((ext_vector_type(4))) float f32x4;
typedef __attribute__((ext_vector_type(16))) float f32x16;

#define VMCNT4 asm volatile("s_waitcnt vmcnt(4)" ::: "memory")
#define VMCNT3 asm volatile("s_waitcnt vmcnt(3)" ::: "memory")
#define VMCNT2 asm volatile("s_waitcnt vmcnt(2)" ::: "memory")
#define VMCNT0 asm volatile("s_waitcnt vmcnt(0)" ::: "memory")
#define LGKM0 asm volatile("s_waitcnt lgkmcnt(0)" ::: "memory")
#define CFENCE asm volatile("" ::: "memory")

__device__ __forceinline__ unsigned short f2bf(float f) {
  unsigned int u = __builtin_bit_cast(unsigned int, f);
  u += 0x7fffu + ((u >> 16) & 1u);
  return (unsigned short)(u >> 16);
}
__device__ __forceinline__ float bf2f(unsigned short h) {
  unsigned int u = ((unsigned int)h) << 16;
  return __builtin_bit_cast(float, u);
}
__device__ __forceinline__ void gload16(const void* g, void* l) {
  __builtin_amdgcn_global_load_lds((const __attribute__((address_space(1))) unsigned int*)g,
                                   (__attribute__((address_space(3))) unsigned int*)l, 16, 0, 0);
}

// ---------------------------------------------------------------------------
// P0rho: one pass over rho per p:
//   R2[p][jk(112 pad)][m(1024)] bf16 (plain slots, 224 MiB)
//   S[p][m] = sum_j rho[p][j][m][j]  (f32, fused diagonal, shfl-paired)
// ---------------------------------------------------------------------------
__launch_bounds__(256)
__global__ void p0_rho(const float* __restrict__ rho, ushort_t* __restrict__ R2,
                       float* __restrict__ S) {
  __shared__ ushort_t R_s[112 * 128];
  int p = blockIdx.x;
  int t = threadIdx.x;
  const float* rp = rho + (size_t)p * (DY * DX * DY);
  ushort_t* R2p = R2 + (size_t)p * (112 * 1024);
  int m = t >> 1, h = t & 1;

  for (int mc = 0; mc < 8; ++mc) {
    __syncthreads();
    float ssum = 0.f;
#pragma unroll
    for (int j = 0; j < DY; ++j) {
      const float* bj = rp + (size_t)j * (DX * DY) + (size_t)(mc * 128 + m) * DY;
      const float4 q = *(const float4*)(bj + h * 4);
      const float e = bj[8 + h];
      int rb = j * DY + h * 4;
      R_s[((rb + 0) * 128 + m) ^ (((rb + 0) & 15) << 3)] = f2bf(q.x);
      R_s[((rb + 1) * 128 + m) ^ (((rb + 1) & 15) << 3)] = f2bf(q.y);
      R_s[((rb + 2) * 128 + m) ^ (((rb + 2) & 15) << 3)] = f2bf(q.z);
      R_s[((rb + 3) * 128 + m) ^ (((rb + 3) & 15) << 3)] = f2bf(q.w);
      int r8 = j * DY + 8 + h;
      R_s[(r8 * 128 + m) ^ ((r8 & 15) << 3)] = f2bf(e);
      if (h == 0) {
        if (j == 0) ssum += q.x;
        if (j == 1) ssum += q.y;
        if (j == 2) ssum += q.z;
        if (j == 3) ssum += q.w;
        if (j == 8) ssum += e;
      } else {
        if (j == 4) ssum += q.x;
        if (j == 5) ssum += q.y;
        if (j == 6) ssum += q.z;
        if (j == 7) ssum += q.w;
        if (j == 9) ssum += e;
      }
    }
    ssum += __shfl_xor(ssum, 1, 64);
    if (h == 0) S[(size_t)p * DX + mc * 128 + m] = ssum;
    __syncthreads();
#pragma unroll
    for (int i = 0; i < 7; ++i) {
      int c = i * 256 + t;
      int row = c >> 4, sl = c & 15;
      uint4 v = make_uint4(0u, 0u, 0u, 0u);
      if (row < NJK) v = *(const uint4*)&R_s[(row * 128 + sl * 8) ^ ((row & 15) << 3)];
      *(uint4*)(R2p + (size_t)row * 1024 + mc * 128 + sl * 8) = v;
    }
  }
}

// ---------------------------------------------------------------------------
// P0a: emit BOTH operands of K1 pre-split:
//  XHL [b][kt(32)][m(1024)][8 slots x 16B] : record = [Ah k0..31 | Al k0..31]
//  XtHL[b][kt(32)][p(1024)][8 slots x 16B] : same for X^T rows.
// ---------------------------------------------------------------------------
__launch_bounds__(256)
__global__ void p0_split(const float* __restrict__ X,
                         ushort_t* __restrict__ XHL, ushort_t* __restrict__ XtHL) {
  __shared__ float T[64][65];
  int blk = blockIdx.x;
  int bl = blk >> 8;
  int tt = blk & 255;
  int r0 = (tt >> 4) << 6;
  int c0 = (tt & 15) << 6;
  const float* Xb = X + (size_t)bl * DX * DX;
  int t = threadIdx.x;
  int r = t >> 4, c = t & 15;
#pragma unroll
  for (int s = 0; s < 4; ++s) {
    const float4 v = *(const float4*)(Xb + (size_t)(r0 + r + 16 * s) * DX + c0 + c * 4);
    T[r + 16 * s][c * 4 + 0] = v.x;
    T[r + 16 * s][c * 4 + 1] = v.y;
    T[r + 16 * s][c * 4 + 2] = v.z;
    T[r + 16 * s][c * 4 + 3] = v.w;
  }
  __syncthreads();
  int s8 = t & 7;
  int rw = t >> 3;
  int isLo = s8 >> 2, q = s8 & 3;
#pragma unroll
  for (int ktl = 0; ktl < 2; ++ktl) {
#pragma unroll
    for (int sp = 0; sp < 2; ++sp) {
      int loc = rw + sp * 32;
      {
        unsigned short hh8[8];
#pragma unroll
        for (int e = 0; e < 8; ++e) {
          float x = T[loc][ktl * 32 + q * 8 + e];
          unsigned short hh = f2bf(x);
          hh8[e] = isLo ? f2bf(x - bf2f(hh)) : hh;
        }
        int kt = (c0 >> 5) + ktl;
        size_t off = (((size_t)bl * 32 + kt) * 1024 + (r0 + loc)) * 64 + s8 * 8;
        uint4 v;
        v.x = (unsigned)hh8[0] | ((unsigned)hh8[1] << 16);
        v.y = (unsigned)hh8[2] | ((unsigned)hh8[3] << 16);
        v.z = (unsigned)hh8[4] | ((unsigned)hh8[5] << 16);
        v.w = (unsigned)hh8[6] | ((unsigned)hh8[7] << 16);
        *(uint4*)(XHL + off) = v;
      }
      {
        unsigned short hh8[8];
#pragma unroll
        for (int e = 0; e < 8; ++e) {
          float x = T[ktl * 32 + q * 8 + e][loc];
          unsigned short hh = f2bf(x);
          hh8[e] = isLo ? f2bf(x - bf2f(hh)) : hh;
        }
        int kt = (r0 >> 5) + ktl;
        size_t off = (((size_t)bl * 32 + kt) * 1024 + (c0 + loc)) * 64 + s8 * 8;
        uint4 v;
        v.x = (unsigned)hh8[0] | ((unsigned)hh8[1] << 16);
        v.y = (unsigned)hh8[2] | ((unsigned)hh8[3] << 16);
        v.z = (unsigned)hh8[4] | ((unsigned)hh8[5] << 16);
        v.w = (unsigned)hh8[6] | ((unsigned)hh8[7] << 16);
        *(uint4*)(XtHL + off) = v;
      }
    }
  }
}

// ---------------------------------------------------------------------------
// K1 (R10 verbatim): 3-pass split-bf16, 256x256 tile, BK=32, 8 waves,
// 8-phase K-step, split staging, counted drains vmcnt(4)/vmcnt(0).
// Epilogue 1: EXACT trace partial = <f32 acc, S[p,m]> -> part_tr[b*16+tile].
// Epilogue 2: Ah bf16 -> [p][b][m] via LDS transpose (coalesced).
// ---------------------------------------------------------------------------
__launch_bounds__(512, 2)
__global__ void k1_gemm(const ushort_t* __restrict__ XHL,
                        const ushort_t* __restrict__ XtHL,
                        const float* __restrict__ S,
                        ushort_t* __restrict__ Ahg,
                        float* __restrict__ part_tr, int bg) {
  __shared__ ushort_t lds[65536];  // 2 bufs x (A 16384 | B 16384) ushorts
  int wg = blockIdx.x;
  int cpx = gridDim.x >> 3;
  int gt = (wg & 7) * cpx + (wg >> 3);  // XCD-chunked
  int bl = gt >> 4, tile = gt & 15;
  int b = bg + bl;
  int m0 = (tile >> 2) << 8, p0 = (tile & 3) << 8;
  int t = threadIdx.x;
  int wv = t >> 6, lane = t & 63, l31 = lane & 31, hi8 = lane >> 5;
  int wm = (wv >> 2) << 7, wp = (wv & 3) << 6;

  f32x16 acc[4][2];
#pragma unroll
  for (int mi = 0; mi < 4; ++mi)
#pragma unroll
    for (int ni = 0; ni < 2; ++ni)
#pragma unroll
      for (int e = 0; e < 16; ++e) acc[mi][ni][e] = 0.f;

  int lam = lane >> 3;
  int lsl = (lane & 7) ^ lam;
  const ushort_t* Asrc = XHL + ((size_t)bl * 32 * 1024 + m0) * 64 + (size_t)lsl * 8;
  const ushort_t* Bsrc = XtHL + ((size_t)bl * 32 * 1024 + p0) * 64 + (size_t)lsl * 8;
  int ldsw = (t & ~63) * 8;

  auto stageA2 = [&](int kt, int half) {
    int buf = (kt & 1) << 15;
    size_t ko = (size_t)kt * 65536;
#pragma unroll
    for (int i = half * 2; i < half * 2 + 2; ++i) {
      int rr = (i << 6) + (wv << 3) + lam;
      gload16(Asrc + ko + (size_t)rr * 64, &lds[buf + (i << 12) + ldsw]);
    }
  };
  auto stageB2 = [&](int kt, int half) {
    int buf = (kt & 1) << 15;
    size_t ko = (size_t)kt * 65536;
#pragma unroll
    for (int i = half * 2; i < half * 2 + 2; ++i) {
      int rr = (i << 6) + (wv << 3) + lam;
      gload16(Bsrc + ko + (size_t)rr * 64, &lds[buf + 16384 + (i << 12) + ldsw]);
    }
  };
  auto readB = [&](int buf, int kc, short8* bh, short8* blo) {
#pragma unroll
    for (int ni = 0; ni < 2; ++ni) {
      int p = wp + (ni << 5) + l31;
      int rowb = buf + 16384 + p * 64;
      bh[ni] = *(const short8*)&lds[rowb + (((kc * 2 + hi8) ^ (p & 7)) << 3)];
      blo[ni] = *(const short8*)&lds[rowb + (((4 + kc * 2 + hi8) ^ (p & 7)) << 3)];
    }
  };
  auto readA2 = [&](int buf, int kc, int mi, short8& a, short8& l) {
    int m = wm + (mi << 5) + l31;
    int rowa = buf + m * 64;
    a = *(const short8*)&lds[rowa + (((kc * 2 + hi8) ^ (m & 7)) << 3)];
    l = *(const short8*)&lds[rowa + (((4 + kc * 2 + hi8) ^ (m & 7)) << 3)];
  };
  auto mfma6 = [&](int mi, const short8& a, const short8& l,
                   const short8* bh, const short8* blo) {
    __builtin_amdgcn_s_setprio(1);
#pragma unroll
    for (int ni = 0; ni < 2; ++ni) {
      acc[mi][ni] = __builtin_amdgcn_mfma_f32_32x32x16_bf16(a, bh[ni], acc[mi][ni], 0, 0, 0);
      acc[mi][ni] = __builtin_amdgcn_mfma_f32_32x32x16_bf16(a, blo[ni], acc[mi][ni], 0, 0, 0);
      acc[mi][ni] = __builtin_amdgcn_mfma_f32_32x32x16_bf16(l, bh[ni], acc[mi][ni], 0, 0, 0);
    }
    __builtin_amdgcn_s_setprio(0);
  };

  stageA2(0, 0);
  stageA2(0, 1);
  stageB2(0, 0);
  stageB2(0, 1);
  VMCNT0;
  __builtin_amdgcn_s_barrier();

#pragma unroll 1
  for (int kt = 0; kt < 32; ++kt) {
    int buf = (kt & 1) << 15;
    short8 bh[2], blo[2], a, l;
    readB(buf, 0, bh, blo);
    readA2(buf, 0, 0, a, l);
    if (kt < 31) stageA2(kt + 1, 0);
    CFENCE; __builtin_amdgcn_s_barrier(); LGKM0; __builtin_amdgcn_sched_barrier(0);
    mfma6(0, a, l, bh, blo);
    readA2(buf, 0, 1, a, l);
    if (kt < 31) stageA2(kt + 1, 1);
    CFENCE; __builtin_amdgcn_s_barrier(); LGKM0; __builtin_amdgcn_sched_barrier(0);
    mfma6(1, a, l, bh, blo);
    readA2(buf, 0, 2, a, l);
    if (kt < 31) stageB2(kt + 1, 0);
    CFENCE; __builtin_amdgcn_s_barrier(); LGKM0; __builtin_amdgcn_sched_barrier(0);
    mfma6(2, a, l, bh, blo);
    readA2(buf, 0, 3, a, l);
    if (kt < 31) stageB2(kt + 1, 1);
    CFENCE; __builtin_amdgcn_s_barrier(); LGKM0; __builtin_amdgcn_sched_barrier(0);
    mfma6(3, a, l, bh, blo);
    readB(buf, 1, bh, blo);
    readA2(buf, 1, 0, a, l);
    CFENCE; __builtin_amdgcn_s_barrier(); LGKM0; __builtin_amdgcn_sched_barrier(0);
    mfma6(0, a, l, bh, blo);
    readA2(buf, 1, 1, a, l);
    if (kt < 31) { VMCNT4; }
    CFENCE; __builtin_amdgcn_s_barrier(); LGKM0; __builtin_amdgcn_sched_barrier(0);
    mfma6(1, a, l, bh, blo);
    readA2(buf, 1, 2, a, l);
    CFENCE; __builtin_amdgcn_s_barrier(); LGKM0; __builtin_amdgcn_sched_barrier(0);
    mfma6(2, a, l, bh, blo);
    readA2(buf, 1, 3, a, l);
    VMCNT0;
    CFENCE; __builtin_amdgcn_s_barrier(); LGKM0; __builtin_amdgcn_sched_barrier(0);
    mfma6(3, a, l, bh, blo);
  }

  // ---- epilogue 1: EXACT trace partial from f32 accumulator ----
  float tracc = 0.f;
#pragma unroll
  for (int mi = 0; mi < 4; ++mi)
#pragma unroll
    for (int ni = 0; ni < 2; ++ni) {
      int p = p0 + wp + (ni << 5) + l31;
#pragma unroll
      for (int rg = 0; rg < 4; ++rg) {
        int m = m0 + wm + (mi << 5) + 8 * rg + 4 * hi8;
        const float4 sv = *(const float4*)(S + (size_t)p * DX + m);
        tracc += acc[mi][ni][rg * 4 + 0] * sv.x + acc[mi][ni][rg * 4 + 1] * sv.y +
                 acc[mi][ni][rg * 4 + 2] * sv.z + acc[mi][ni][rg * 4 + 3] * sv.w;
      }
    }
#pragma unroll
  for (int off = 32; off > 0; off >>= 1) tracc += __shfl_xor(tracc, off, 64);
  __syncthreads();
  if (lane == 0) ((float*)lds)[wv] = tracc;
  __syncthreads();
  if (t == 0) {
    float s = 0.f;
    for (int i = 0; i < 8; ++i) s += ((float*)lds)[i];
    part_tr[b * 16 + tile] = s;
  }
  __syncthreads();

  // ---- epilogue 2: Ah -> LDS [p][m] (swizzled) -> coalesced 16B stores ----
#pragma unroll
  for (int mi = 0; mi < 4; ++mi)
#pragma unroll
    for (int ni = 0; ni < 2; ++ni) {
      int p = wp + (ni << 5) + l31;
#pragma unroll
      for (int rg = 0; rg < 4; ++rg) {
        int m = wm + (mi << 5) + 8 * rg + 4 * hi8;
        unsigned int h0 = f2bf(acc[mi][ni][rg * 4 + 0]);
        unsigned int h1 = f2bf(acc[mi][ni][rg * 4 + 1]);
        unsigned int h2 = f2bf(acc[mi][ni][rg * 4 + 2]);
        unsigned int h3 = f2bf(acc[mi][ni][rg * 4 + 3]);
        int idx = p * 256 + (((m >> 3) ^ (p & 7)) << 3) + (m & 7);
        *(uint2*)&lds[idx] = make_uint2(h0 | (h1 << 16), h2 | (h3 << 16));
      }
    }
  __syncthreads();
#pragma unroll
  for (int i = 0; i < 16; ++i) {
    int cc = i * 512 + t;
    int row = cc >> 5, sl = cc & 31;
    int idx = row * 256 + ((sl ^ (row & 7)) << 3);
    uint4 v = *(const uint4*)&lds[idx];
    *(uint4*)(Ahg + ((size_t)(p0 + row) * NB + b) * DX + m0 + sl * 8) = v;
  }
}

// ---------------------------------------------------------------------------
// K2: numerator. One block per p: C[b,jk] += Ah[b,m]*R2[jk,m], K=1024.
// mc chunks of 32 m -> 22.5 KB LDS -> ALL 1024 blocks co-resident (4/CU).
// Pure gload16 staging, dbuf, per-wave counted vmcnt (wv0-2: 3, wv3: 2).
// ---------------------------------------------------------------------------
__launch_bounds__(256)
__global__ void k2_contract(const ushort_t* __restrict__ R2,
                            const ushort_t* __restrict__ Ahg,
                            float* __restrict__ part_rho) {
  __shared__ ushort_t lds[11264];  // 2 bufs x (A 2048 | B 3584) ushorts
  int p = blockIdx.x;
  int t = threadIdx.x;
  int wv = t >> 6, lane = t & 63, lr = lane & 15, lg = lane >> 4;
  const ushort_t* R2p = R2 + (size_t)p * (112 * 1024);
  const ushort_t* Ahp = Ahg + (size_t)p * (NB * DX);

  f32x4 acc[7];
#pragma unroll
  for (int n = 0; n < 7; ++n)
#pragma unroll
    for (int i = 0; i < 4; ++i) acc[n][i] = 0.f;

  auto stage = [&](int mc) {
    int buf = (mc & 1) * 5632;
    // A: 64 b-rows x 32 m (4 slots/row), 1 load/thread
    {
      int br = t >> 2, psl = t & 3;
      int lsl = psl ^ (br & 3);
      gload16(Ahp + (size_t)br * DX + mc * 32 + lsl * 8,
              &lds[buf + (t & ~63) * 8]);
    }
    // B: 112 jk-rows x 32 m, 448 loads (wv0-2: 2/thread, wv3: 1)
#pragma unroll
    for (int i = 0; i < 2; ++i) {
      int c = i * 256 + t;
      if (c < 448) {
        int row = c >> 2, psl = c & 3;
        int lsl = psl ^ (row & 3);
        gload16(R2p + (size_t)row * 1024 + mc * 32 + lsl * 8,
                &lds[buf + 2048 + (i * 256 + (t & ~63)) * 8]);
      }
    }
  };

  stage(0);
#pragma unroll 1
  for (int mc = 0; mc < 32; ++mc) {
    int buf = (mc & 1) * 5632;
    if (mc < 31) {
      stage(mc + 1);
      if (wv < 3) { VMCNT3; } else { VMCNT2; }
    } else {
      VMCNT0;
    }
    __builtin_amdgcn_s_barrier();
    CFENCE;
    {
      int ra = 16 * wv + lr;
      short8 af = *(const short8*)&lds[buf + ra * 32 + ((lg ^ (ra & 3)) << 3)];
      __builtin_amdgcn_s_setprio(1);
#pragma unroll
      for (int n = 0; n < 7; ++n) {
        int rb = 16 * n + lr;
        short8 bf = *(const short8*)&lds[buf + 2048 + rb * 32 + ((lg ^ (rb & 3)) << 3)];
        acc[n] = __builtin_amdgcn_mfma_f32_16x16x32_bf16(af, bf, acc[n], 0, 0, 0);
      }
      __builtin_amdgcn_s_setprio(0);
    }
    CFENCE;
    __builtin_amdgcn_s_barrier();
  }
#pragma unroll
  for (int n = 0; n < 7; ++n) {
    int col = 16 * n + lr;
    if (col < NJK) {
#pragma unroll
      for (int i = 0; i < 4; ++i) {
        int b_ = 16 * wv + lg * 4 + i;
        part_rho[((size_t)p * NB + b_) * NJK + col] = acc[n][i];
      }
    }
  }
}

// ---------------------------------------------------------------------------
// K3a: partial p-reduction; K3b: finish + divide by EXACT trace.
// ---------------------------------------------------------------------------
__launch_bounds__(128)
__global__ void k3a(const float* __restrict__ part_rho, float* __restrict__ ws2) {
  int blk = blockIdx.x;
  int b = blk >> 1, h = blk & 1;
  int t = threadIdx.x;
  if (t >= NJK) return;
  float s = 0.f;
  for (int pp = 0; pp < 512; ++pp)
    s += part_rho[((size_t)(h * 512 + pp) * NB + b) * NJK + t];
  ws2[(size_t)(h * NB + b) * 128 + t] = s;
}

__launch_bounds__(128)
__global__ void k3b(const float* __restrict__ ws2, const float* __restrict__ part_tr,
                    float* __restrict__ out) {
  int b = blockIdx.x;
  int t = threadIdx.x;
  float tr = 0.f;
#pragma unroll
  for (int i = 0; i < 16; ++i) tr += part_tr[b * 16 + i];
  if (t < NJK) {
    float v = ws2[(size_t)b * 128 + t] + ws2[(size_t)(NB + b) * 128 + t];
    out[b * NJK + t] = v / tr;
  }
}

extern "C" void kernel_launch(void* const* d_in, const int* in_sizes, int n_in,
                              void* d_out, int out_size, void* d_ws, size_t ws_size,
                              hipStream_t stream) {
  const float* X = (const float*)d_in[0];
  const float* rho = (const float*)d_in[1];
  float* out = (float*)d_out;
  char* ws = (char*)d_ws;

  const size_t MB = 1048576ull;
  const size_t need_big = 868 * MB + 65536;
  const size_t need_small = 484 * MB + 65536;

  if (ws_size >= need_big) {
    ushort_t* XHL = (ushort_t*)(ws);              // 256 MiB
    ushort_t* XtHL = (ushort_t*)(ws + 256 * MB);  // 256 MiB
    ushort_t* Ahg = (ushort_t*)(ws + 512 * MB);   // 128 MiB
    ushort_t* R2 = (ushort_t*)(ws + 640 * MB);    // 224 MiB
    float* S = (float*)(ws + 864 * MB);           // 4 MiB
    float* part_tr = (float*)(ws + 868 * MB);     // 4 KiB
    float* part_rho = (float*)(ws);               // overlays XHL (dead after k1)
    float* ws2 = (float*)(ws + 32 * MB);

    hipLaunchKernelGGL(p0_rho, dim3(1024), dim3(256), 0, stream, rho, R2, S);
    hipLaunchKernelGGL(p0_split, dim3(16384), dim3(256), 0, stream, X, XHL, XtHL);
    hipLaunchKernelGGL(k1_gemm, dim3(1024), dim3(512), 0, stream, XHL, XtHL, S, Ahg, part_tr, 0);
    hipLaunchKernelGGL(k2_contract, dim3(1024), dim3(256), 0, stream, R2, Ahg, part_rho);
    hipLaunchKernelGGL(k3a, dim3(128), dim3(128), 0, stream, part_rho, ws2);
    hipLaunchKernelGGL(k3b, dim3(64), dim3(128), 0, stream, ws2, part_tr, out);
  } else {
    ushort_t* XHL = (ushort_t*)(ws);
    ushort_t* XtHL = (ushort_t*)(ws + 64 * MB);
    ushort_t* Ahg = (ushort_t*)(ws + 128 * MB);
    ushort_t* R2 = (ushort_t*)(ws + 256 * MB);
    float* S = (float*)(ws + 480 * MB);
    float* part_tr = (float*)(ws + 484 * MB);
    float* part_rho = (float*)(ws);
    float* ws2 = (float*)(ws + 32 * MB);
    if (ws_size < need_small) return;

    hipLaunchKernelGGL(p0_rho, dim3(1024), dim3(256), 0, stream, rho, R2, S);
    for (int g = 0; g < 4; ++g) {
      hipLaunchKernelGGL(p0_split, dim3(4096), dim3(256), 0, stream,
                         X + (size_t)g * 16 * DX * DX, XHL, XtHL);
      hipLaunchKernelGGL(k1_gemm, dim3(256), dim3(512), 0, stream, XHL, XtHL, S, Ahg, part_tr, g * 16);
    }
    hipLaunchKernelGGL(k2_contract, dim3(1024), dim3(256), 0, stream, R2, Ahg, part_rho);
    hipLaunchKernelGGL(k3a, dim3(128), dim3(128), 0, stream, part_rho, ws2);
    hipLaunchKernelGGL(k3b, dim3(64), dim3(128), 0, stream, ws2, part_tr, out);
  }
}